// Round 2
// baseline (291.637 us; speedup 1.0000x reference)
//
#include <hip/hip_runtime.h>

// Adaptive separable conv: out[b,c,y,x] = sum_i sum_j inp[b,c,y+i,x+j]*v[b,i,y,x]*h[b,j,y,x]
// B=2,C=3,H=W=256,K=51, fp32. No MFMA (per-pixel weights; no fp32 MFMA on CDNA4).
//
// R2: occupancy-focused restructure.
//  - 512-thread blocks (8 waves), i-taps split 8 ways across waves (7,7,7,6,6,6,6,6).
//  - Per thread: R=4 x-adjacent outputs x 3 channels, BI=2 i-taps per register block.
//  - Rolling 8-float window per (c,ib): one ds_read_b128 per 4 j-taps -> 16 FMAs/read.
//  - No nx prefetch regs (direct LDS re-read); h double-buffer prefetch (compile-time
//    masked tail since j0 loop is fully unrolled).
//  - __launch_bounds__(512,4) caps VGPR at 128 -> 2 blocks/CU (LDS 57.5KB x2) = 16 waves/CU.

namespace {
constexpr int KK = 51;
constexpr int NB = 2;
constexpr int NC = 3;
constexpr int HH = 256;
constexpr int WW = 256;
constexpr int IN_H = HH + KK - 1;   // 306
constexpr int IN_W = WW + KK - 1;   // 306

constexpr int TILE_W = 32;          // output cols per block
constexpr int TILE_H = 8;           // output rows per block
constexpr int NTX = 8;              // threads along x (each covers R=4 outputs)
constexpr int R = 4;
constexpr int NTY = 8;
constexpr int NS = 8;               // i-tap split across the 8 waves
constexpr int NTHREADS = NTX * NTY * NS;      // 512
constexpr int HALO_W = TILE_W + KK - 1;       // 82
constexpr int LDS_W = 84;                     // 82 valid + 2 zero pad
constexpr int LDS_H = TILE_H + KK - 1;        // 58
constexpr int BI = 2;               // i-taps per register block
}

__device__ __forceinline__ float fget(const float4 v, int i) {
  return (i == 0) ? v.x : (i == 1) ? v.y : (i == 2) ? v.z : v.w;
}

__global__ __launch_bounds__(NTHREADS, 4) void sepconv_kernel(
    const float* __restrict__ inp,
    const float* __restrict__ vert,
    const float* __restrict__ horiz,
    float* __restrict__ out)
{
  __shared__ float lds[NC * LDS_H * LDS_W];   // 58,464 B

  const int tid = threadIdx.x;
  const int tx  = tid & (NTX - 1);
  const int ty  = (tid >> 3) & (NTY - 1);
  const int s   = tid >> 6;                    // wave id: 0..7 (wave-uniform)

  const int x0 = blockIdx.x * TILE_W;
  const int y0 = blockIdx.y * TILE_H;
  const int bz = blockIdx.z;

  // ---- Stage input tile: 3ch x 58 rows x 82 cols (float2), zero the 2 pad cols.
  {
    const float* src = inp + ((size_t)(bz * NC) * IN_H + y0) * IN_W + x0;
    const int total2 = NC * LDS_H * (HALO_W / 2);   // 3*58*41 = 7134
    for (int e = tid; e < total2; e += NTHREADS) {
      int col2 = e % (HALO_W / 2);
      int t    = e / (HALO_W / 2);
      int r    = t % LDS_H;
      int c    = t / LDS_H;
      const float2 v = *reinterpret_cast<const float2*>(src + ((size_t)c * IN_H + r) * IN_W + col2 * 2);
      float* dst = &lds[(c * LDS_H + r) * LDS_W + col2 * 2];
      dst[0] = v.x; dst[1] = v.y;
    }
    for (int e = tid; e < NC * LDS_H * (LDS_W - HALO_W); e += NTHREADS) {
      int p = e % (LDS_W - HALO_W);
      int t = e / (LDS_W - HALO_W);
      int r = t % LDS_H;
      int c = t / LDS_H;
      lds[(c * LDS_H + r) * LDS_W + HALO_W + p] = 0.0f;
    }
  }
  __syncthreads();

  const int lx = tx * R;                 // local LDS col base (16B aligned)
  const int xg = x0 + lx;
  const int yg = y0 + ty;

  float acc[R][NC];
#pragma unroll
  for (int rx = 0; rx < R; ++rx)
#pragma unroll
    for (int c = 0; c < NC; ++c) acc[rx][c] = 0.0f;

  // i-tap split: waves 0..2 -> 7 taps, waves 3..7 -> 6 taps (3*7 + 5*6 = 51)
  const int sbase  = (s < 3) ? 7 * s : 21 + 6 * (s - 3);
  const int scount = (s < 3) ? 7 : 6;
  const int nblk   = (s < 3) ? 4 : 3;           // ceil(scount/BI), wave-uniform

  const float* vbase = vert  + (((size_t)bz * KK) * HH + yg) * WW + xg;
  const float* hbase = horiz + (((size_t)bz * KK) * HH + yg) * WW + xg;
  constexpr int KSTRIDE = HH * WW;

  for (int i0 = 0; i0 < nblk; ++i0) {
    const int ibase = sbase + i0 * BI;

    // Per-block vertical weights (read-once). Masked tail slot -> 0.
    float4 v4[BI];
#pragma unroll
    for (int ib = 0; ib < BI; ++ib) {
      const int i = ibase + ib;
      float4 t = *reinterpret_cast<const float4*>(vbase + (size_t)i * KSTRIDE);
      if (i >= sbase + scount) t = make_float4(0.f, 0.f, 0.f, 0.f);
      v4[ib] = t;
    }

    // Init rolling windows: w = lds cols [lx, lx+8)
    float w[NC][BI][8];
#pragma unroll
    for (int c = 0; c < NC; ++c) {
#pragma unroll
      for (int ib = 0; ib < BI; ++ib) {
        const int rr = ty + ibase + ib;    // <= 7 + 50 = 57 (masked i <= 21), in bounds
        const float4* p = reinterpret_cast<const float4*>(&lds[(c * LDS_H + rr) * LDS_W + lx]);
        float4 a = p[0], b = p[1];
        w[c][ib][0] = a.x; w[c][ib][1] = a.y; w[c][ib][2] = a.z; w[c][ib][3] = a.w;
        w[c][ib][4] = b.x; w[c][ib][5] = b.y; w[c][ib][6] = b.z; w[c][ib][7] = b.w;
      }
    }

    // Prefetch h for chunk j0=0
    float4 h4[4];
#pragma unroll
    for (int jj = 0; jj < 4; ++jj)
      h4[jj] = *reinterpret_cast<const float4*>(hbase + (size_t)jj * KSTRIDE);

#pragma unroll
    for (int j0 = 0; j0 < 52; j0 += 4) {   // 13 chunks of 4 j-taps, fully unrolled
      float4 hc[4];
#pragma unroll
      for (int jj = 0; jj < 4; ++jj) hc[jj] = h4[jj];

      // Prefetch next chunk's h. j0, jj are compile-time -> tail mask folds statically.
      if (j0 < 48) {
#pragma unroll
        for (int jj = 0; jj < 4; ++jj) {
          const int j = j0 + 4 + jj;
          if (j <= 50) {
            h4[jj] = *reinterpret_cast<const float4*>(hbase + (size_t)j * KSTRIDE);
          } else {
            h4[jj] = make_float4(0.f, 0.f, 0.f, 0.f);
          }
        }
      }

      // coeff = v*h hoisted across 3 channels: 32 muls + 96 FMAs per chunk
#pragma unroll
      for (int rx = 0; rx < R; ++rx) {
#pragma unroll
        for (int ib = 0; ib < BI; ++ib) {
          const float vv = fget(v4[ib], rx);
#pragma unroll
          for (int jj = 0; jj < 4; ++jj) {
            const float cf = vv * fget(hc[jj], rx);
#pragma unroll
            for (int c = 0; c < NC; ++c)
              acc[rx][c] = fmaf(cf, w[c][ib][rx + jj], acc[rx][c]);
          }
        }
      }

      // Shift window by 4 and load next quad directly from LDS (no prefetch regs).
      if (j0 < 48) {
#pragma unroll
        for (int c = 0; c < NC; ++c) {
#pragma unroll
          for (int ib = 0; ib < BI; ++ib) {
#pragma unroll
            for (int q = 0; q < 4; ++q) w[c][ib][q] = w[c][ib][q + 4];
            const int rr = ty + ibase + ib;
            const float4 n = *reinterpret_cast<const float4*>(
                &lds[(c * LDS_H + rr) * LDS_W + lx + j0 + 8]);
            w[c][ib][4] = n.x; w[c][ib][5] = n.y; w[c][ib][6] = n.z; w[c][ib][7] = n.w;
          }
        }
      }
    }
  }

  // ---- Reduce the 8 i-split partials (waves 1..7 -> LDS, wave 0 adds & stores)
  __syncthreads();   // all LDS inp reads done; safe to reuse
  if (s > 0) {
    float* p = &lds[((s - 1) * 64 + (tid & 63)) * 12];
#pragma unroll
    for (int rx = 0; rx < R; ++rx)
#pragma unroll
      for (int c = 0; c < NC; ++c) p[rx * 3 + c] = acc[rx][c];
  }
  __syncthreads();
  if (s == 0) {
#pragma unroll
    for (int g = 0; g < 7; ++g) {
      const float* p = &lds[(g * 64 + (tid & 63)) * 12];
#pragma unroll
      for (int rx = 0; rx < R; ++rx)
#pragma unroll
        for (int c = 0; c < NC; ++c) acc[rx][c] += p[rx * 3 + c];
    }
#pragma unroll
    for (int c = 0; c < NC; ++c) {
      float4 o = make_float4(acc[0][c], acc[1][c], acc[2][c], acc[3][c]);
      *reinterpret_cast<float4*>(out + (((size_t)bz * NC + c) * HH + yg) * WW + xg) = o;
    }
  }
}

extern "C" void kernel_launch(void* const* d_in, const int* in_sizes, int n_in,
                              void* d_out, int out_size, void* d_ws, size_t ws_size,
                              hipStream_t stream) {
  const float* inp   = (const float*)d_in[0];
  const float* vert  = (const float*)d_in[1];
  const float* horiz = (const float*)d_in[2];
  float* out = (float*)d_out;

  dim3 grid(WW / TILE_W, HH / TILE_H, NB);   // 8 x 32 x 2 = 512 blocks
  sepconv_kernel<<<grid, NTHREADS, 0, stream>>>(inp, vert, horiz, out);
}